// Round 1
// baseline (119.650 us; speedup 1.0000x reference)
//
#include <hip/hip_runtime.h>

// Problem constants (from reference)
#define NITEMS 100000
#define NRATE  5
#define BB     4096
#define LL     200
#define DD     64
#define NTILES 6250   // 6250*16 = 100000 exactly

typedef short short8  __attribute__((ext_vector_type(8)));
typedef float f32x4   __attribute__((ext_vector_type(4)));
typedef float f32x2   __attribute__((ext_vector_type(2)));
typedef int   i32x4   __attribute__((ext_vector_type(4)));

// RTNA (round-half-away) fp32->bf16: bits+0x8000, take top 16. Max err 0.5 ulp.
static __device__ __forceinline__ short f2bf(float f) {
  return (short)((__builtin_bit_cast(unsigned, f) + 0x8000u) >> 16);
}
// pack two fp32 -> dword {lo=bf16(a), hi=bf16(b)} : 2 adds + 1 v_perm_b32
static __device__ __forceinline__ unsigned pk2bf(float a, float b) {
  const unsigned ua = __builtin_bit_cast(unsigned, a) + 0x8000u;
  const unsigned ub = __builtin_bit_cast(unsigned, b) + 0x8000u;
  return __builtin_amdgcn_perm(ub, ua, 0x07060302u);
}
// k-space permutation: storage position p holds h-component pi(p)=(p&3)*16+(p>>2).
static __device__ __forceinline__ int kperm(int p) {
  return ((p & 3) << 4) | (p >> 2);
}

#if __has_builtin(__builtin_elementwise_max)
static __device__ __forceinline__ f32x2 relu2(f32x2 v) {
  return __builtin_elementwise_max(v, f32x2{0.f, 0.f});   // v_pk_max_f32
}
static __device__ __forceinline__ f32x4 relu4(f32x4 v) {
  return __builtin_elementwise_max(v, f32x4{0.f, 0.f, 0.f, 0.f});
}
#else
static __device__ __forceinline__ f32x2 relu2(f32x2 v) {
  return f32x2{fmaxf(v.x, 0.f), fmaxf(v.y, 0.f)};
}
static __device__ __forceinline__ f32x4 relu4(f32x4 v) {
  return f32x4{fmaxf(v[0], 0.f), fmaxf(v[1], 0.f), fmaxf(v[2], 0.f), fmaxf(v[3], 0.f)};
}
#endif

// ---------------------------------------------------------------------------
// k_pre: block 0 = prep (w2p, r5p); blocks 1..1563: ONE 16-item tile per wave
// (6250 waves total, no software pipeline -> 3x the wave count of the old
// 512-block version; latency hidden by TLP instead of a 3-4 deep pipeline).
//   pre8[item] : 64 B of e4m3 fp8. Byte q = quad*16 + kh*8 + j holds
//   permuted-k position p = kh*32 + quad*8 + j, i.e. orig dim pi(p).
// ---------------------------------------------------------------------------
__global__ __launch_bounds__(256) void k_pre(
    const float* __restrict__ v2e, const float* __restrict__ r2e,
    const float* __restrict__ w1W, const float* __restrict__ w1b,
    const float* __restrict__ w2W,
    unsigned char* __restrict__ pre8, short* __restrict__ w2p,
    float* __restrict__ r5p)
{
  const int tid = threadIdx.x;
  const int blk = blockIdx.x;

  if (blk == 0) {   // prep block FIRST so it overlaps the table build
    for (int idx = tid; idx < 64 * 64; idx += 256) {
      const int o = idx >> 6, p = idx & 63;
      w2p[idx] = f2bf(w2W[o * 64 + kperm(p)]);
    }
    for (int idx = tid; idx < NRATE * 64; idx += 256) {
      const int r = idx >> 6, p = idx & 63;
      const int o = kperm(p);
      const float4* wr = reinterpret_cast<const float4*>(w1W + o * 128 + 64);
      const float4* rr = reinterpret_cast<const float4*>(r2e + r * 64);
      float s = w1b[o];
#pragma unroll
      for (int q = 0; q < 16; ++q) {
        const float4 a = wr[q], b = rr[q];
        s += a.x * b.x + a.y * b.y + a.z * b.z + a.w * b.w;
      }
      r5p[r * 64 + p] = s;
    }
    return;
  }

  const int wave = tid >> 6, lane = tid & 63;
  const int n = lane & 15, quad = lane >> 4;
  const int tile = (blk - 1) * 4 + wave;      // 0..6251; 2 idle waves
  if (tile >= NTILES) return;

  // Lane (n,quad) produces orig dims o = nt*16+n -> perm pos p = 4n+nt ->
  // byte q0+nt with q0 = ((n>>1)&3)*16 + (n>>3)*8 + (n&1)*4 (one dword).
  const int q0 = ((n >> 1) & 3) * 16 + (n >> 3) * 8 + (n & 1) * 4;

  // issue the HBM v2e loads first; bfr (L2-hot w1W) fills the latency gap
  const size_t row = (size_t)(tile * 16 + n);
  const float4* pv = reinterpret_cast<const float4*>(v2e + row * 64 + quad * 8);
  const float4* qv = reinterpret_cast<const float4*>(v2e + row * 64 + 32 + quad * 8);
  const float4 cur0 = pv[0], cur1 = pv[1], cur2 = qv[0], cur3 = qv[1];

  // B fragment: B[k][o], k = kh*32 + quad*8 + j
  short8 bfr[2][4];
#pragma unroll
  for (int nt = 0; nt < 4; ++nt)
#pragma unroll
    for (int kh = 0; kh < 2; ++kh) {
      const float4* p = reinterpret_cast<const float4*>(
          w1W + (nt * 16 + n) * 128 + kh * 32 + quad * 8);
      const float4 x0 = p[0], x1 = p[1];
      i32x4 pk = {(int)pk2bf(x0.x, x0.y), (int)pk2bf(x0.z, x0.w),
                  (int)pk2bf(x1.x, x1.y), (int)pk2bf(x1.z, x1.w)};
      bfr[kh][nt] = __builtin_bit_cast(short8, pk);
    }

  short8 afr[2];
  {
    i32x4 pk0 = {(int)pk2bf(cur0.x, cur0.y), (int)pk2bf(cur0.z, cur0.w),
                 (int)pk2bf(cur1.x, cur1.y), (int)pk2bf(cur1.z, cur1.w)};
    afr[0] = __builtin_bit_cast(short8, pk0);
    i32x4 pk1 = {(int)pk2bf(cur2.x, cur2.y), (int)pk2bf(cur2.z, cur2.w),
                 (int)pk2bf(cur3.x, cur3.y), (int)pk2bf(cur3.z, cur3.w)};
    afr[1] = __builtin_bit_cast(short8, pk1);
  }

  f32x4 d[4];
#pragma unroll
  for (int nt = 0; nt < 4; ++nt) {
    f32x4 z = {0.f, 0.f, 0.f, 0.f};
    z = __builtin_amdgcn_mfma_f32_16x16x32_bf16(afr[0], bfr[0][nt], z, 0, 0, 0);
    z = __builtin_amdgcn_mfma_f32_16x16x32_bf16(afr[1], bfr[1][nt], z, 0, 0, 0);
    d[nt] = z;
  }

  // C/D: lane (n,quad), reg (nt,r) = item quad*4+r (of tile), dim nt*16+n.
  const int ib = tile * 16;
#pragma unroll
  for (int r = 0; r < 4; ++r) {
    const int item = ib + quad * 4 + r;
    int pkd = 0;
    pkd = __builtin_amdgcn_cvt_pk_fp8_f32(d[0][r], d[1][r], pkd, false);
    pkd = __builtin_amdgcn_cvt_pk_fp8_f32(d[2][r], d[3][r], pkd, true);
    *reinterpret_cast<int*>(pre8 + (size_t)item * 64 + q0) = pkd;
  }
}

// ---------------------------------------------------------------------------
// k_main: TWO waves per b (2048 blocks x 4 waves = 8192 waves). Wave-half 0
// does tiles 0..6, half 1 does tiles 7..12 (tail). Halves the serial
// 13-tile dependency chain per wave and halves the gather-prefetch VGPRs;
// cross-wave combine via a tiny LDS reduce + one barrier.
// ---------------------------------------------------------------------------
template<int T0, int NT>
static __device__ __forceinline__ void mbody(
    const unsigned char* __restrict__ pre8,
    const int* __restrict__ hu, const int* __restrict__ hr,
    const float* __restrict__ r5w,
    const short8 (&bfr)[2][4], const f32x4 (&zb)[4],
    const int n, const int quad, const float tailm,
    f32x4 (&acc4)[4])
{
  int ivv[NT], irr[NT];
#pragma unroll
  for (int k = 0; k < NT; ++k) {
    const int t = T0 + k;
    const int l = (t == 12) ? min(192 + n, LL - 1) : (t * 16 + n);
    ivv[k] = hu[l];
    irr[k] = hr[l];
  }

  // all fp8 gathers in flight before compute
  i32x4 g[NT];
#pragma unroll
  for (int k = 0; k < NT; ++k)
    g[k] = *reinterpret_cast<const i32x4*>(
        pre8 + (size_t)ivv[k] * 64 + quad * 16);

#pragma unroll
  for (int k = 0; k < NT; ++k) {
    const float* rbase = r5w + irr[k] * 68 + quad * 8;
    short8 afr[2];
    // kh = 0: dwords g[k][0..1], r5 at +0
    {
      const f32x2* rp = reinterpret_cast<const f32x2*>(rbase);
      f32x2 p0 = relu2(__builtin_amdgcn_cvt_pk_f32_fp8(g[k][0], false) + rp[0]);
      f32x2 p1 = relu2(__builtin_amdgcn_cvt_pk_f32_fp8(g[k][0], true)  + rp[1]);
      f32x2 p2 = relu2(__builtin_amdgcn_cvt_pk_f32_fp8(g[k][1], false) + rp[2]);
      f32x2 p3 = relu2(__builtin_amdgcn_cvt_pk_f32_fp8(g[k][1], true)  + rp[3]);
      i32x4 hpk = {(int)pk2bf(p0.x, p0.y), (int)pk2bf(p1.x, p1.y),
                   (int)pk2bf(p2.x, p2.y), (int)pk2bf(p3.x, p3.y)};
      afr[0] = __builtin_bit_cast(short8, hpk);
    }
    // kh = 1: dwords g[k][2..3], r5 at +32
    {
      const f32x2* rp = reinterpret_cast<const f32x2*>(rbase + 32);
      f32x2 p0 = relu2(__builtin_amdgcn_cvt_pk_f32_fp8(g[k][2], false) + rp[0]);
      f32x2 p1 = relu2(__builtin_amdgcn_cvt_pk_f32_fp8(g[k][2], true)  + rp[1]);
      f32x2 p2 = relu2(__builtin_amdgcn_cvt_pk_f32_fp8(g[k][3], false) + rp[2]);
      f32x2 p3 = relu2(__builtin_amdgcn_cvt_pk_f32_fp8(g[k][3], true)  + rp[3]);
      i32x4 hpk = {(int)pk2bf(p0.x, p0.y), (int)pk2bf(p1.x, p1.y),
                   (int)pk2bf(p2.x, p2.y), (int)pk2bf(p3.x, p3.y)};
      afr[1] = __builtin_bit_cast(short8, hpk);
    }

    f32x4 d[4];
#pragma unroll
    for (int nt = 0; nt < 4; ++nt) {
      f32x4 z = zb[nt];
      z = __builtin_amdgcn_mfma_f32_16x16x32_bf16(afr[0], bfr[0][nt], z, 0, 0, 0);
      z = __builtin_amdgcn_mfma_f32_16x16x32_bf16(afr[1], bfr[1][nt], z, 0, 0, 0);
      d[nt] = z;
    }

#pragma unroll
    for (int nt = 0; nt < 4; ++nt) {
      f32x4 mx = relu4(d[nt]);              // 2x v_pk_max_f32
      if (T0 + k == 12) mx = mx * tailm;    // tail tile: rows m>=8 invalid
      acc4[nt] += mx;                        // 2x v_pk_add_f32
    }
  }
}

__global__ __launch_bounds__(256) void k_main(
    const unsigned char* __restrict__ pre8, const float* __restrict__ r5p,
    const short* __restrict__ w2p, const float* __restrict__ w2b,
    const int* __restrict__ huv, const int* __restrict__ hrr,
    float* __restrict__ out)
{
  __shared__ __align__(16) float s_r5[4][5 * 68];   // per-wave copy, no barrier
  __shared__ float red[4][64];

  const int tid  = threadIdx.x;
  const int wave = tid >> 6, lane = tid & 63;
  const int n = lane & 15, quad = lane >> 4;
  const int hlf = wave & 1;
  const int b = blockIdx.x * 2 + (wave >> 1);

  // wave-private r5 copy (5*64 = 320, 5 iters of 64 lanes)
#pragma unroll
  for (int i = 0; i < 5; ++i) {
    const int idx = i * 64 + lane;
    s_r5[wave][(idx >> 6) * 68 + (idx & 63)] = r5p[idx];
  }

  const int* hu = huv + b * LL;
  const int* hr = hrr + b * LL;

  // B fragments for W2 (permuted k-space): B[p][o] = w2p[o*64+p]
  short8 bfr[2][4];
#pragma unroll
  for (int nt = 0; nt < 4; ++nt)
#pragma unroll
    for (int kh = 0; kh < 2; ++kh)
      bfr[kh][nt] = *reinterpret_cast<const short8*>(
          w2p + (nt * 16 + n) * 64 + kh * 32 + quad * 8);

  // bias folded into MFMA C-init
  f32x4 zb[4];
#pragma unroll
  for (int nt = 0; nt < 4; ++nt) {
    const float bv = w2b[nt * 16 + n];
    zb[nt] = f32x4{bv, bv, bv, bv};
  }

  const float tailm = (quad < 2) ? 1.0f : 0.0f;  // tile-12 valid rows: m<8
  f32x4 acc4[4] = {{0.f,0.f,0.f,0.f},{0.f,0.f,0.f,0.f},
                   {0.f,0.f,0.f,0.f},{0.f,0.f,0.f,0.f}};

  if (hlf == 0)
    mbody<0, 7>(pre8, hu, hr, &s_r5[wave][0], bfr, zb, n, quad, tailm, acc4);
  else
    mbody<7, 6>(pre8, hu, hr, &s_r5[wave][0], bfr, zb, n, quad, tailm, acc4);

  // collapse regs, sum across the 4 quads -> every lane has all 4 sums
  float acc[4];
#pragma unroll
  for (int nt = 0; nt < 4; ++nt) {
    float v = (acc4[nt][0] + acc4[nt][1]) + (acc4[nt][2] + acc4[nt][3]);
    v += __shfl_xor(v, 16, 64);
    v += __shfl_xor(v, 32, 64);
    acc[nt] = v;
  }

  // cross-wave (half0 + half1) combine via LDS
  red[wave][quad * 16 + n] = acc[quad];
  __syncthreads();
  if (wave < 2) {
    const int bb = blockIdx.x * 2 + wave;
    out[bb * 64 + lane] =
        (red[2 * wave][lane] + red[2 * wave + 1][lane]) * (1.0f / (float)LL);
  }
}

// ---------------------------------------------------------------------------
// Fallback (no workspace): all-fp32, one block per b, weights in padded LDS.
// ---------------------------------------------------------------------------
__global__ __launch_bounds__(256) void k_fallback(
    const float* __restrict__ v2e, const float* __restrict__ r2e,
    const float* __restrict__ w1W, const float* __restrict__ w1b,
    const float* __restrict__ w2W, const float* __restrict__ w2b,
    const int* __restrict__ huv, const int* __restrict__ hrr,
    float* __restrict__ out)
{
  __shared__ float sw1[64][129];
  __shared__ float sw2[64][65];
  __shared__ float sx[4][128];
  __shared__ float sh[4][64];
  __shared__ float red[4][64];

  const int tid = threadIdx.x;
  const int wave = tid >> 6, lane = tid & 63;
  const int b = blockIdx.x;

  for (int idx = tid; idx < 64 * 128; idx += 256) sw1[idx >> 7][idx & 127] = w1W[idx];
  for (int idx = tid; idx < 64 * 64; idx += 256) sw2[idx >> 6][idx & 63] = w2W[idx];
  __syncthreads();

  const float b1o = w1b[lane], b2o = w2b[lane];
  float acc = 0.f;

  for (int l = wave; l < LL; l += 4) {
    const int iv = huv[b * LL + l];
    const int ir = hrr[b * LL + l];
    sx[wave][lane]      = v2e[iv * 64 + lane];
    sx[wave][64 + lane] = r2e[ir * 64 + lane];
    __syncthreads();
    float h = b1o;
    for (int i = 0; i < 128; ++i) h += sx[wave][i] * sw1[lane][i];
    sh[wave][lane] = fmaxf(h, 0.f);
    __syncthreads();
    float o = b2o;
    for (int i = 0; i < 64; ++i) o += sh[wave][i] * sw2[lane][i];
    acc += fmaxf(o, 0.f);
  }

  red[wave][lane] = acc;
  __syncthreads();
  if (tid < 64) {
    const float s = red[0][tid] + red[1][tid] + red[2][tid] + red[3][tid];
    out[b * 64 + tid] = s * (1.0f / (float)LL);
  }
}

extern "C" void kernel_launch(void* const* d_in, const int* in_sizes, int n_in,
                              void* d_out, int out_size, void* d_ws, size_t ws_size,
                              hipStream_t stream) {
  (void)in_sizes; (void)n_in; (void)out_size;
  const float* v2e = (const float*)d_in[0];   // [100000,64]
  const float* r2e = (const float*)d_in[1];   // [5,64]
  const float* w1W = (const float*)d_in[2];   // [64,128]
  const float* w1b = (const float*)d_in[3];   // [64]
  const float* w2W = (const float*)d_in[4];   // [64,64]
  const float* w2b = (const float*)d_in[5];   // [64]
  // d_in[6] = nodes (unused by uv=True branch)
  const int* huv = (const int*)d_in[7];       // [4096,200]
  const int* hrr = (const int*)d_in[8];       // [4096,200]
  float* out = (float*)d_out;                 // [4096,64]

  const size_t OFF_R5 = (size_t)NITEMS * 64;                   // 6,400,000 (fp8 table)
  const size_t OFF_W2 = OFF_R5 + NRATE * 64 * sizeof(float);   // +1,280
  const size_t NEED   = OFF_W2 + 64 * 64 * sizeof(short);      // +8,192

  if (ws_size >= NEED) {
    unsigned char* pre8 = (unsigned char*)d_ws;
    float* r5p = (float*)((char*)d_ws + OFF_R5);
    short* w2p = (short*)((char*)d_ws + OFF_W2);

    k_pre<<<1564, 256, 0, stream>>>(v2e, r2e, w1W, w1b, w2W, pre8, w2p, r5p);
    k_main<<<BB / 2, 256, 0, stream>>>(pre8, r5p, w2p, w2b, huv, hrr, out);
  } else {
    k_fallback<<<BB, 256, 0, stream>>>(v2e, r2e, w1W, w1b, w2W, w2b, huv, hrr, out);
  }
}

// Round 3
// 116.951 us; speedup vs baseline: 1.0231x; 1.0231x over previous
//
#include <hip/hip_runtime.h>

// Problem constants (from reference)
#define NITEMS 100000
#define NRATE  5
#define BB     4096
#define LL     200
#define DD     64
#define NTILES 6250   // 6250*16 = 100000 exactly

typedef short short8  __attribute__((ext_vector_type(8)));
typedef float f32x4   __attribute__((ext_vector_type(4)));
typedef float f32x2   __attribute__((ext_vector_type(2)));
typedef int   i32x4   __attribute__((ext_vector_type(4)));

// RTNA (round-half-away) fp32->bf16: bits+0x8000, take top 16. Max err 0.5 ulp.
// NOTE: round-2 tried inline-asm v_cvt_pk_bf16_f32 here -> absmax 8e34 garbage.
// Keep the v_perm-based pack; it is known-good (114 us baseline).
static __device__ __forceinline__ short f2bf(float f) {
  return (short)((__builtin_bit_cast(unsigned, f) + 0x8000u) >> 16);
}
// pack two fp32 -> dword {lo=bf16(a), hi=bf16(b)} : 2 adds + 1 v_perm_b32
static __device__ __forceinline__ unsigned pk2bf(float a, float b) {
  const unsigned ua = __builtin_bit_cast(unsigned, a) + 0x8000u;
  const unsigned ub = __builtin_bit_cast(unsigned, b) + 0x8000u;
  return __builtin_amdgcn_perm(ub, ua, 0x07060302u);
}
// k-space permutation: storage position p holds h-component pi(p)=(p&3)*16+(p>>2).
static __device__ __forceinline__ int kperm(int p) {
  return ((p & 3) << 4) | (p >> 2);
}

#if __has_builtin(__builtin_elementwise_max)
static __device__ __forceinline__ f32x2 relu2(f32x2 v) {
  return __builtin_elementwise_max(v, f32x2{0.f, 0.f});   // v_pk_max_f32
}
static __device__ __forceinline__ f32x4 relu4(f32x4 v) {
  return __builtin_elementwise_max(v, f32x4{0.f, 0.f, 0.f, 0.f});
}
#else
static __device__ __forceinline__ f32x2 relu2(f32x2 v) {
  return f32x2{fmaxf(v.x, 0.f), fmaxf(v.y, 0.f)};
}
static __device__ __forceinline__ f32x4 relu4(f32x4 v) {
  return f32x4{fmaxf(v[0], 0.f), fmaxf(v[1], 0.f), fmaxf(v[2], 0.f), fmaxf(v[3], 0.f)};
}
#endif

// ---------------------------------------------------------------------------
// k_pre: block 0 = prep (w2p, r5p); blocks 1..1563: ONE 16-item tile per wave
// (6250 waves; latency hidden by TLP).
//   pre8[item] : 64 B of e4m3 fp8. Byte q = quad*16 + kh*8 + j holds
//   permuted-k position p = kh*32 + quad*8 + j, i.e. orig dim pi(p).
// ---------------------------------------------------------------------------
__global__ __launch_bounds__(256) void k_pre(
    const float* __restrict__ v2e, const float* __restrict__ r2e,
    const float* __restrict__ w1W, const float* __restrict__ w1b,
    const float* __restrict__ w2W,
    unsigned char* __restrict__ pre8, short* __restrict__ w2p,
    float* __restrict__ r5p)
{
  const int tid = threadIdx.x;
  const int blk = blockIdx.x;

  if (blk == 0) {   // prep block: w2p (bf16, permuted) + r5p (fp32, permuted)
    for (int idx = tid; idx < 64 * 64; idx += 256) {
      const int o = idx >> 6, p = idx & 63;
      w2p[idx] = f2bf(w2W[o * 64 + kperm(p)]);
    }
    for (int idx = tid; idx < NRATE * 64; idx += 256) {
      const int r = idx >> 6, p = idx & 63;
      const int o = kperm(p);
      const float4* wr = reinterpret_cast<const float4*>(w1W + o * 128 + 64);
      const float4* rr = reinterpret_cast<const float4*>(r2e + r * 64);
      float s = w1b[o];
#pragma unroll
      for (int q = 0; q < 16; ++q) {
        const float4 a = wr[q], b = rr[q];
        s += a.x * b.x + a.y * b.y + a.z * b.z + a.w * b.w;
      }
      r5p[r * 64 + p] = s;
    }
    return;
  }

  const int wave = tid >> 6, lane = tid & 63;
  const int n = lane & 15, quad = lane >> 4;
  const int tile = (blk - 1) * 4 + wave;      // 0..6251; 2 idle waves
  if (tile >= NTILES) return;

  // Lane (n,quad) produces orig dims o = nt*16+n -> perm pos p = 4n+nt ->
  // byte q0+nt with q0 = ((n>>1)&3)*16 + (n>>3)*8 + (n&1)*4 (one dword).
  const int q0 = ((n >> 1) & 3) * 16 + (n >> 3) * 8 + (n & 1) * 4;

  // issue the HBM v2e loads first; bfr (L2-hot w1W) fills the latency gap
  const size_t row = (size_t)(tile * 16 + n);
  const float4* pv = reinterpret_cast<const float4*>(v2e + row * 64 + quad * 8);
  const float4* qv = reinterpret_cast<const float4*>(v2e + row * 64 + 32 + quad * 8);
  const float4 cur0 = pv[0], cur1 = pv[1], cur2 = qv[0], cur3 = qv[1];

  // B fragment: B[k][o], k = kh*32 + quad*8 + j
  short8 bfr[2][4];
#pragma unroll
  for (int nt = 0; nt < 4; ++nt)
#pragma unroll
    for (int kh = 0; kh < 2; ++kh) {
      const float4* p = reinterpret_cast<const float4*>(
          w1W + (nt * 16 + n) * 128 + kh * 32 + quad * 8);
      const float4 x0 = p[0], x1 = p[1];
      i32x4 pk = {(int)pk2bf(x0.x, x0.y), (int)pk2bf(x0.z, x0.w),
                  (int)pk2bf(x1.x, x1.y), (int)pk2bf(x1.z, x1.w)};
      bfr[kh][nt] = __builtin_bit_cast(short8, pk);
    }

  short8 afr[2];
  {
    i32x4 pk0 = {(int)pk2bf(cur0.x, cur0.y), (int)pk2bf(cur0.z, cur0.w),
                 (int)pk2bf(cur1.x, cur1.y), (int)pk2bf(cur1.z, cur1.w)};
    afr[0] = __builtin_bit_cast(short8, pk0);
    i32x4 pk1 = {(int)pk2bf(cur2.x, cur2.y), (int)pk2bf(cur2.z, cur2.w),
                 (int)pk2bf(cur3.x, cur3.y), (int)pk2bf(cur3.z, cur3.w)};
    afr[1] = __builtin_bit_cast(short8, pk1);
  }

  f32x4 d[4];
#pragma unroll
  for (int nt = 0; nt < 4; ++nt) {
    f32x4 z = {0.f, 0.f, 0.f, 0.f};
    z = __builtin_amdgcn_mfma_f32_16x16x32_bf16(afr[0], bfr[0][nt], z, 0, 0, 0);
    z = __builtin_amdgcn_mfma_f32_16x16x32_bf16(afr[1], bfr[1][nt], z, 0, 0, 0);
    d[nt] = z;
  }

  // C/D: lane (n,quad), reg (nt,r) = item quad*4+r (of tile), dim nt*16+n.
  const int ib = tile * 16;
#pragma unroll
  for (int r = 0; r < 4; ++r) {
    const int item = ib + quad * 4 + r;
    int pkd = 0;
    pkd = __builtin_amdgcn_cvt_pk_fp8_f32(d[0][r], d[1][r], pkd, false);
    pkd = __builtin_amdgcn_cvt_pk_fp8_f32(d[2][r], d[3][r], pkd, true);
    *reinterpret_cast<int*>(pre8 + (size_t)item * 64 + q0) = pkd;
  }
}

// ---------------------------------------------------------------------------
// k_main: wave-per-b (1024 blocks x 4 waves), 13 l-tiles per wave; idx loads
// and ALL 13 16-B fp8 gathers issued before any other work. fp8->f32 via
// v_cvt_pk_f32_fp8, + r5 (fp32, LDS, wave-private copy -> no barrier),
// relu (v_pk_max), bf16 pack via pk2bf, layer-2 bf16 MFMA with bias folded
// into C-init. Tail tile 12 masked. Packed-math epilogue.
// ---------------------------------------------------------------------------
__global__ __launch_bounds__(256) void k_main(
    const unsigned char* __restrict__ pre8, const float* __restrict__ r5p,
    const short* __restrict__ w2p, const float* __restrict__ w2b,
    const int* __restrict__ huv, const int* __restrict__ hrr,
    float* __restrict__ out)
{
  __shared__ __align__(16) float s_r5[4][5 * 68];   // per-wave copy, no barrier

  const int tid  = threadIdx.x;
  const int wave = tid >> 6, lane = tid & 63;
  const int n = lane & 15, quad = lane >> 4;
  const int b = blockIdx.x * 4 + wave;

  const int* hu = huv + b * LL;
  const int* hr = hrr + b * LL;

  // tile t covers rows l = t*16 + n. Tail tile 12: l = 192..199.
  int iv[13], ir[13];
#pragma unroll
  for (int t = 0; t < 12; ++t) {
    iv[t] = hu[t * 16 + n];
    ir[t] = hr[t * 16 + n];
  }
  {
    const int lc = min(192 + n, LL - 1);
    iv[12] = hu[lc];
    ir[12] = hr[lc];
  }

  // issue ALL fp8 gathers (13 independent 16-B loads in flight per wave);
  // lane (n,quad) takes bytes [quad*16, quad*16+16) of item row iv[t].
  i32x4 g[13];
#pragma unroll
  for (int t = 0; t < 13; ++t)
    g[t] = *reinterpret_cast<const i32x4*>(
        pre8 + (size_t)iv[t] * 64 + quad * 16);

  // wave-private r5 copy (5*64 = 320, 5 iters of 64 lanes) — after the
  // gathers so the serial idx->gather chain starts as early as possible
#pragma unroll
  for (int i = 0; i < 5; ++i) {
    const int idx = i * 64 + lane;
    s_r5[wave][(idx >> 6) * 68 + (idx & 63)] = r5p[idx];
  }

  // B fragments for W2 (permuted k-space): B[p][o] = w2p[o*64+p]
  short8 bfr[2][4];
#pragma unroll
  for (int nt = 0; nt < 4; ++nt)
#pragma unroll
    for (int kh = 0; kh < 2; ++kh)
      bfr[kh][nt] = *reinterpret_cast<const short8*>(
          w2p + (nt * 16 + n) * 64 + kh * 32 + quad * 8);

  // bias folded into MFMA C-init
  f32x4 zb[4];
#pragma unroll
  for (int nt = 0; nt < 4; ++nt) {
    const float bv = w2b[nt * 16 + n];
    zb[nt] = f32x4{bv, bv, bv, bv};
  }

  const float tailm = (quad < 2) ? 1.0f : 0.0f;  // tile-12 valid rows: m<8
  f32x4 acc4[4] = {{0.f,0.f,0.f,0.f},{0.f,0.f,0.f,0.f},
                   {0.f,0.f,0.f,0.f},{0.f,0.f,0.f,0.f}};

#pragma unroll
  for (int t = 0; t < 13; ++t) {
    const float* rbase = &s_r5[wave][ir[t] * 68 + quad * 8];
    short8 afr[2];
    // kh = 0: dwords g[t][0..1], r5 at +0
    {
      const f32x2* rp = reinterpret_cast<const f32x2*>(rbase);
      f32x2 p0 = relu2(__builtin_amdgcn_cvt_pk_f32_fp8(g[t][0], false) + rp[0]);
      f32x2 p1 = relu2(__builtin_amdgcn_cvt_pk_f32_fp8(g[t][0], true)  + rp[1]);
      f32x2 p2 = relu2(__builtin_amdgcn_cvt_pk_f32_fp8(g[t][1], false) + rp[2]);
      f32x2 p3 = relu2(__builtin_amdgcn_cvt_pk_f32_fp8(g[t][1], true)  + rp[3]);
      i32x4 hpk = {(int)pk2bf(p0.x, p0.y), (int)pk2bf(p1.x, p1.y),
                   (int)pk2bf(p2.x, p2.y), (int)pk2bf(p3.x, p3.y)};
      afr[0] = __builtin_bit_cast(short8, hpk);
    }
    // kh = 1: dwords g[t][2..3], r5 at +32
    {
      const f32x2* rp = reinterpret_cast<const f32x2*>(rbase + 32);
      f32x2 p0 = relu2(__builtin_amdgcn_cvt_pk_f32_fp8(g[t][2], false) + rp[0]);
      f32x2 p1 = relu2(__builtin_amdgcn_cvt_pk_f32_fp8(g[t][2], true)  + rp[1]);
      f32x2 p2 = relu2(__builtin_amdgcn_cvt_pk_f32_fp8(g[t][3], false) + rp[2]);
      f32x2 p3 = relu2(__builtin_amdgcn_cvt_pk_f32_fp8(g[t][3], true)  + rp[3]);
      i32x4 hpk = {(int)pk2bf(p0.x, p0.y), (int)pk2bf(p1.x, p1.y),
                   (int)pk2bf(p2.x, p2.y), (int)pk2bf(p3.x, p3.y)};
      afr[1] = __builtin_bit_cast(short8, hpk);
    }

    f32x4 d[4];
#pragma unroll
    for (int nt = 0; nt < 4; ++nt) {
      f32x4 z = zb[nt];
      z = __builtin_amdgcn_mfma_f32_16x16x32_bf16(afr[0], bfr[0][nt], z, 0, 0, 0);
      z = __builtin_amdgcn_mfma_f32_16x16x32_bf16(afr[1], bfr[1][nt], z, 0, 0, 0);
      d[nt] = z;
    }

#pragma unroll
    for (int nt = 0; nt < 4; ++nt) {
      f32x4 mx = relu4(d[nt]);              // 2x v_pk_max_f32
      if (t == 12) mx = mx * tailm;         // tail tile: rows m>=8 invalid
      acc4[nt] += mx;                        // 2x v_pk_add_f32
    }
  }

  // collapse regs, sum across the 4 quads -> every lane has all 4 sums
  float acc[4];
#pragma unroll
  for (int nt = 0; nt < 4; ++nt) {
    float v = (acc4[nt][0] + acc4[nt][1]) + (acc4[nt][2] + acc4[nt][3]);
    v += __shfl_xor(v, 16, 64);
    v += __shfl_xor(v, 32, 64);
    acc[nt] = v;
  }

  // coalesced: lane (n,quad) stores column quad*16+n (one dword per lane)
  out[b * 64 + quad * 16 + n] = acc[quad] * (1.0f / (float)LL);
}

// ---------------------------------------------------------------------------
// Fallback (no workspace): all-fp32, one block per b, weights in padded LDS.
// ---------------------------------------------------------------------------
__global__ __launch_bounds__(256) void k_fallback(
    const float* __restrict__ v2e, const float* __restrict__ r2e,
    const float* __restrict__ w1W, const float* __restrict__ w1b,
    const float* __restrict__ w2W, const float* __restrict__ w2b,
    const int* __restrict__ huv, const int* __restrict__ hrr,
    float* __restrict__ out)
{
  __shared__ float sw1[64][129];
  __shared__ float sw2[64][65];
  __shared__ float sx[4][128];
  __shared__ float sh[4][64];
  __shared__ float red[4][64];

  const int tid = threadIdx.x;
  const int wave = tid >> 6, lane = tid & 63;
  const int b = blockIdx.x;

  for (int idx = tid; idx < 64 * 128; idx += 256) sw1[idx >> 7][idx & 127] = w1W[idx];
  for (int idx = tid; idx < 64 * 64; idx += 256) sw2[idx >> 6][idx & 63] = w2W[idx];
  __syncthreads();

  const float b1o = w1b[lane], b2o = w2b[lane];
  float acc = 0.f;

  for (int l = wave; l < LL; l += 4) {
    const int iv = huv[b * LL + l];
    const int ir = hrr[b * LL + l];
    sx[wave][lane]      = v2e[iv * 64 + lane];
    sx[wave][64 + lane] = r2e[ir * 64 + lane];
    __syncthreads();
    float h = b1o;
    for (int i = 0; i < 128; ++i) h += sx[wave][i] * sw1[lane][i];
    sh[wave][lane] = fmaxf(h, 0.f);
    __syncthreads();
    float o = b2o;
    for (int i = 0; i < 64; ++i) o += sh[wave][i] * sw2[lane][i];
    acc += fmaxf(o, 0.f);
  }

  red[wave][lane] = acc;
  __syncthreads();
  if (tid < 64) {
    const float s = red[0][tid] + red[1][tid] + red[2][tid] + red[3][tid];
    out[b * 64 + tid] = s * (1.0f / (float)LL);
  }
}

extern "C" void kernel_launch(void* const* d_in, const int* in_sizes, int n_in,
                              void* d_out, int out_size, void* d_ws, size_t ws_size,
                              hipStream_t stream) {
  (void)in_sizes; (void)n_in; (void)out_size;
  const float* v2e = (const float*)d_in[0];   // [100000,64]
  const float* r2e = (const float*)d_in[1];   // [5,64]
  const float* w1W = (const float*)d_in[2];   // [64,128]
  const float* w1b = (const float*)d_in[3];   // [64]
  const float* w2W = (const float*)d_in[4];   // [64,64]
  const float* w2b = (const float*)d_in[5];   // [64]
  // d_in[6] = nodes (unused by uv=True branch)
  const int* huv = (const int*)d_in[7];       // [4096,200]
  const int* hrr = (const int*)d_in[8];       // [4096,200]
  float* out = (float*)d_out;                 // [4096,64]

  const size_t OFF_R5 = (size_t)NITEMS * 64;                   // 6,400,000 (fp8 table)
  const size_t OFF_W2 = OFF_R5 + NRATE * 64 * sizeof(float);   // +1,280
  const size_t NEED   = OFF_W2 + 64 * 64 * sizeof(short);      // +8,192

  if (ws_size >= NEED) {
    unsigned char* pre8 = (unsigned char*)d_ws;
    float* r5p = (float*)((char*)d_ws + OFF_R5);
    short* w2p = (short*)((char*)d_ws + OFF_W2);

    k_pre<<<1564, 256, 0, stream>>>(v2e, r2e, w1W, w1b, w2W, pre8, w2p, r5p);
    k_main<<<BB / 4, 256, 0, stream>>>(pre8, r5p, w2p, w2b, huv, hrr, out);
  } else {
    k_fallback<<<BB, 256, 0, stream>>>(v2e, r2e, w1W, w1b, w2W, w2b, huv, hrr, out);
  }
}

// Round 4
// 113.494 us; speedup vs baseline: 1.0542x; 1.0305x over previous
//
#include <hip/hip_runtime.h>

// Problem constants (from reference)
#define NITEMS 100000
#define NRATE  5
#define BB     4096
#define LL     200
#define DD     64
#define NTILES 6250   // 6250*16 = 100000 exactly
#define NWAVES 3128   // 782 worker blocks * 4 waves; 3 waves/SIMD
#define NW_REM 3122   // waves [0, NW_REM) do 2 tiles, rest do 1  (2*3122+6=6250)

typedef short short8  __attribute__((ext_vector_type(8)));
typedef float f32x4   __attribute__((ext_vector_type(4)));
typedef float f32x2   __attribute__((ext_vector_type(2)));
typedef int   i32x4   __attribute__((ext_vector_type(4)));

// RTNA (round-half-away) fp32->bf16: bits+0x8000, take top 16. Max err 0.5 ulp.
// NOTE: round-2 tried inline-asm v_cvt_pk_bf16_f32 here -> absmax 8e34 garbage.
// Keep the v_perm-based pack; it is known-good.
static __device__ __forceinline__ short f2bf(float f) {
  return (short)((__builtin_bit_cast(unsigned, f) + 0x8000u) >> 16);
}
// pack two fp32 -> dword {lo=bf16(a), hi=bf16(b)} : 2 adds + 1 v_perm_b32
static __device__ __forceinline__ unsigned pk2bf(float a, float b) {
  const unsigned ua = __builtin_bit_cast(unsigned, a) + 0x8000u;
  const unsigned ub = __builtin_bit_cast(unsigned, b) + 0x8000u;
  return __builtin_amdgcn_perm(ub, ua, 0x07060302u);
}
// k-space permutation: storage position p holds h-component pi(p)=(p&3)*16+(p>>2).
static __device__ __forceinline__ int kperm(int p) {
  return ((p & 3) << 4) | (p >> 2);
}

#if __has_builtin(__builtin_elementwise_max)
static __device__ __forceinline__ f32x2 relu2(f32x2 v) {
  return __builtin_elementwise_max(v, f32x2{0.f, 0.f});   // v_pk_max_f32
}
static __device__ __forceinline__ f32x4 relu4(f32x4 v) {
  return __builtin_elementwise_max(v, f32x4{0.f, 0.f, 0.f, 0.f});
}
#else
static __device__ __forceinline__ f32x2 relu2(f32x2 v) {
  return f32x2{fmaxf(v.x, 0.f), fmaxf(v.y, 0.f)};
}
static __device__ __forceinline__ f32x4 relu4(f32x4 v) {
  return f32x4{fmaxf(v[0], 0.f), fmaxf(v[1], 0.f), fmaxf(v[2], 0.f), fmaxf(v[3], 0.f)};
}
#endif

// ---------------------------------------------------------------------------
// k_pre: block 0 = prep (w2p, r5p); blocks 1..782: pipelined 2-tile waves
// (3128 waves, bfr amortized over 2 tiles, depth-2 software pipeline).
//   pre8[item] : 64 B of e4m3 fp8. Byte q = quad*16 + kh*8 + j holds
//   permuted-k position p = kh*32 + quad*8 + j, i.e. orig dim pi(p).
// ---------------------------------------------------------------------------
__global__ __launch_bounds__(256) void k_pre(
    const float* __restrict__ v2e, const float* __restrict__ r2e,
    const float* __restrict__ w1W, const float* __restrict__ w1b,
    const float* __restrict__ w2W,
    unsigned char* __restrict__ pre8, short* __restrict__ w2p,
    float* __restrict__ r5p)
{
  const int tid = threadIdx.x;
  const int blk = blockIdx.x;

  if (blk == 0) {   // prep block: w2p (bf16, permuted) + r5p (fp32, permuted)
    for (int idx = tid; idx < 64 * 64; idx += 256) {
      const int o = idx >> 6, p = idx & 63;
      w2p[idx] = f2bf(w2W[o * 64 + kperm(p)]);
    }
    for (int idx = tid; idx < NRATE * 64; idx += 256) {
      const int r = idx >> 6, p = idx & 63;
      const int o = kperm(p);
      const float4* wr = reinterpret_cast<const float4*>(w1W + o * 128 + 64);
      const float4* rr = reinterpret_cast<const float4*>(r2e + r * 64);
      float s = w1b[o];
#pragma unroll
      for (int q = 0; q < 16; ++q) {
        const float4 a = wr[q], b = rr[q];
        s += a.x * b.x + a.y * b.y + a.z * b.z + a.w * b.w;
      }
      r5p[r * 64 + p] = s;
    }
    return;
  }

  const int wave = tid >> 6, lane = tid & 63;
  const int n = lane & 15, quad = lane >> 4;
  const int gw = (blk - 1) * 4 + wave;          // 0..3127
  const int ntile = (gw < NW_REM) ? 2 : 1;

  // Lane (n,quad) produces orig dims o = nt*16+n -> perm pos p = 4n+nt ->
  // byte q0+nt with q0 = ((n>>1)&3)*16 + (n>>3)*8 + (n&1)*4 (one dword).
  const int q0 = ((n >> 1) & 3) * 16 + (n >> 3) * 8 + (n & 1) * 4;

  // issue first tile's HBM loads before the bfr setup so the ~900-cycle
  // v2e miss hides under the 32 L2 loads + packs of bfr
  int tile = gw;
  float4 cur0, cur1, cur2, cur3;
  {
    const size_t row = (size_t)(tile * 16 + n);
    const float4* p = reinterpret_cast<const float4*>(v2e + row * 64 + quad * 8);
    cur0 = p[0]; cur1 = p[1];
    const float4* q = reinterpret_cast<const float4*>(v2e + row * 64 + 32 + quad * 8);
    cur2 = q[0]; cur3 = q[1];
  }

  // B fragment (amortized over ntile MFMA passes): B[k][o], k=kh*32+quad*8+j
  short8 bfr[2][4];
#pragma unroll
  for (int nt = 0; nt < 4; ++nt)
#pragma unroll
    for (int kh = 0; kh < 2; ++kh) {
      const float4* p = reinterpret_cast<const float4*>(
          w1W + (nt * 16 + n) * 128 + kh * 32 + quad * 8);
      const float4 x0 = p[0], x1 = p[1];
      i32x4 pk = {(int)pk2bf(x0.x, x0.y), (int)pk2bf(x0.z, x0.w),
                  (int)pk2bf(x1.x, x1.y), (int)pk2bf(x1.z, x1.w)};
      bfr[kh][nt] = __builtin_bit_cast(short8, pk);
    }

  for (int it = 0; it < ntile; ++it) {
    const int next = tile + NWAVES;
    float4 nx0, nx1, nx2, nx3;
    if (it + 1 < ntile) {
      const size_t row = (size_t)(next * 16 + n);
      const float4* p = reinterpret_cast<const float4*>(v2e + row * 64 + quad * 8);
      nx0 = p[0]; nx1 = p[1];
      const float4* q = reinterpret_cast<const float4*>(v2e + row * 64 + 32 + quad * 8);
      nx2 = q[0]; nx3 = q[1];
    }

    short8 afr[2];
    {
      i32x4 pk0 = {(int)pk2bf(cur0.x, cur0.y), (int)pk2bf(cur0.z, cur0.w),
                   (int)pk2bf(cur1.x, cur1.y), (int)pk2bf(cur1.z, cur1.w)};
      afr[0] = __builtin_bit_cast(short8, pk0);
      i32x4 pk1 = {(int)pk2bf(cur2.x, cur2.y), (int)pk2bf(cur2.z, cur2.w),
                   (int)pk2bf(cur3.x, cur3.y), (int)pk2bf(cur3.z, cur3.w)};
      afr[1] = __builtin_bit_cast(short8, pk1);
    }

    f32x4 d[4];
#pragma unroll
    for (int nt = 0; nt < 4; ++nt) {
      f32x4 z = {0.f, 0.f, 0.f, 0.f};
      z = __builtin_amdgcn_mfma_f32_16x16x32_bf16(afr[0], bfr[0][nt], z, 0, 0, 0);
      z = __builtin_amdgcn_mfma_f32_16x16x32_bf16(afr[1], bfr[1][nt], z, 0, 0, 0);
      d[nt] = z;
    }

    // C/D: lane (n,quad), reg (nt,r) = item quad*4+r (of tile), dim nt*16+n.
    const int ib = tile * 16;
#pragma unroll
    for (int r = 0; r < 4; ++r) {
      const int item = ib + quad * 4 + r;
      int pkd = 0;
      pkd = __builtin_amdgcn_cvt_pk_fp8_f32(d[0][r], d[1][r], pkd, false);
      pkd = __builtin_amdgcn_cvt_pk_fp8_f32(d[2][r], d[3][r], pkd, true);
      *reinterpret_cast<int*>(pre8 + (size_t)item * 64 + q0) = pkd;
    }

    tile = next;
    cur0 = nx0; cur1 = nx1; cur2 = nx2; cur3 = nx3;
  }
}

// ---------------------------------------------------------------------------
// k_main: wave-per-b (1024 blocks x 4 waves), 13 l-tiles per wave; idx loads
// and ALL 13 16-B fp8 gathers issued before any other work. fp8->f32 via
// v_cvt_pk_f32_fp8, + r5 (fp32, LDS, wave-private copy -> no barrier, read
// as f32x4/ds_read_b128), relu (v_pk_max), bf16 pack via pk2bf, layer-2
// bf16 MFMA (setprio(1) around the cluster) with bias folded into C-init.
// Tail tile 12 masked. Packed-math epilogue.
// ---------------------------------------------------------------------------
__global__ __launch_bounds__(256) void k_main(
    const unsigned char* __restrict__ pre8, const float* __restrict__ r5p,
    const short* __restrict__ w2p, const float* __restrict__ w2b,
    const int* __restrict__ huv, const int* __restrict__ hrr,
    float* __restrict__ out)
{
  __shared__ __align__(16) float s_r5[4][5 * 68];   // per-wave copy, no barrier

  const int tid  = threadIdx.x;
  const int wave = tid >> 6, lane = tid & 63;
  const int n = lane & 15, quad = lane >> 4;
  const int b = blockIdx.x * 4 + wave;

  const int* hu = huv + b * LL;
  const int* hr = hrr + b * LL;

  // tile t covers rows l = t*16 + n. Tail tile 12: l = 192..199.
  int iv[13], ir[13];
#pragma unroll
  for (int t = 0; t < 12; ++t) {
    iv[t] = hu[t * 16 + n];
    ir[t] = hr[t * 16 + n];
  }
  {
    const int lc = min(192 + n, LL - 1);
    iv[12] = hu[lc];
    ir[12] = hr[lc];
  }

  // issue ALL fp8 gathers (13 independent 16-B loads in flight per wave);
  // lane (n,quad) takes bytes [quad*16, quad*16+16) of item row iv[t].
  i32x4 g[13];
#pragma unroll
  for (int t = 0; t < 13; ++t)
    g[t] = *reinterpret_cast<const i32x4*>(
        pre8 + (size_t)iv[t] * 64 + quad * 16);

  // wave-private r5 copy (5*64 = 320, 5 iters of 64 lanes) — after the
  // gathers so the serial idx->gather chain starts as early as possible
#pragma unroll
  for (int i = 0; i < 5; ++i) {
    const int idx = i * 64 + lane;
    s_r5[wave][(idx >> 6) * 68 + (idx & 63)] = r5p[idx];
  }

  // B fragments for W2 (permuted k-space): B[p][o] = w2p[o*64+p]
  short8 bfr[2][4];
#pragma unroll
  for (int nt = 0; nt < 4; ++nt)
#pragma unroll
    for (int kh = 0; kh < 2; ++kh)
      bfr[kh][nt] = *reinterpret_cast<const short8*>(
          w2p + (nt * 16 + n) * 64 + kh * 32 + quad * 8);

  // bias folded into MFMA C-init
  f32x4 zb[4];
#pragma unroll
  for (int nt = 0; nt < 4; ++nt) {
    const float bv = w2b[nt * 16 + n];
    zb[nt] = f32x4{bv, bv, bv, bv};
  }

  const float tailm = (quad < 2) ? 1.0f : 0.0f;  // tile-12 valid rows: m<8
  f32x4 acc4[4] = {{0.f,0.f,0.f,0.f},{0.f,0.f,0.f,0.f},
                   {0.f,0.f,0.f,0.f},{0.f,0.f,0.f,0.f}};

#pragma unroll
  for (int t = 0; t < 13; ++t) {
    const float* rbase = &s_r5[wave][ir[t] * 68 + quad * 8];
    // r5 via 16-B LDS reads (row stride 272 B and quad*32 B keep alignment)
    const f32x4 ra = *reinterpret_cast<const f32x4*>(rbase);
    const f32x4 rb = *reinterpret_cast<const f32x4*>(rbase + 4);
    const f32x4 rc = *reinterpret_cast<const f32x4*>(rbase + 32);
    const f32x4 rd = *reinterpret_cast<const f32x4*>(rbase + 36);

    short8 afr[2];
    // kh = 0: dwords g[t][0..1], r5 = ra/rb
    {
      f32x2 p0 = relu2(__builtin_amdgcn_cvt_pk_f32_fp8(g[t][0], false) + f32x2{ra[0], ra[1]});
      f32x2 p1 = relu2(__builtin_amdgcn_cvt_pk_f32_fp8(g[t][0], true)  + f32x2{ra[2], ra[3]});
      f32x2 p2 = relu2(__builtin_amdgcn_cvt_pk_f32_fp8(g[t][1], false) + f32x2{rb[0], rb[1]});
      f32x2 p3 = relu2(__builtin_amdgcn_cvt_pk_f32_fp8(g[t][1], true)  + f32x2{rb[2], rb[3]});
      i32x4 hpk = {(int)pk2bf(p0.x, p0.y), (int)pk2bf(p1.x, p1.y),
                   (int)pk2bf(p2.x, p2.y), (int)pk2bf(p3.x, p3.y)};
      afr[0] = __builtin_bit_cast(short8, hpk);
    }
    // kh = 1: dwords g[t][2..3], r5 = rc/rd
    {
      f32x2 p0 = relu2(__builtin_amdgcn_cvt_pk_f32_fp8(g[t][2], false) + f32x2{rc[0], rc[1]});
      f32x2 p1 = relu2(__builtin_amdgcn_cvt_pk_f32_fp8(g[t][2], true)  + f32x2{rc[2], rc[3]});
      f32x2 p2 = relu2(__builtin_amdgcn_cvt_pk_f32_fp8(g[t][3], false) + f32x2{rd[0], rd[1]});
      f32x2 p3 = relu2(__builtin_amdgcn_cvt_pk_f32_fp8(g[t][3], true)  + f32x2{rd[2], rd[3]});
      i32x4 hpk = {(int)pk2bf(p0.x, p0.y), (int)pk2bf(p1.x, p1.y),
                   (int)pk2bf(p2.x, p2.y), (int)pk2bf(p3.x, p3.y)};
      afr[1] = __builtin_bit_cast(short8, hpk);
    }

    __builtin_amdgcn_s_setprio(1);
    f32x4 d[4];
#pragma unroll
    for (int nt = 0; nt < 4; ++nt) {
      f32x4 z = zb[nt];
      z = __builtin_amdgcn_mfma_f32_16x16x32_bf16(afr[0], bfr[0][nt], z, 0, 0, 0);
      z = __builtin_amdgcn_mfma_f32_16x16x32_bf16(afr[1], bfr[1][nt], z, 0, 0, 0);
      d[nt] = z;
    }
    __builtin_amdgcn_s_setprio(0);

#pragma unroll
    for (int nt = 0; nt < 4; ++nt) {
      f32x4 mx = relu4(d[nt]);              // 2x v_pk_max_f32
      if (t == 12) mx = mx * tailm;         // tail tile: rows m>=8 invalid
      acc4[nt] += mx;                        // 2x v_pk_add_f32
    }
  }

  // collapse regs, sum across the 4 quads -> every lane has all 4 sums
  float acc[4];
#pragma unroll
  for (int nt = 0; nt < 4; ++nt) {
    float v = (acc4[nt][0] + acc4[nt][1]) + (acc4[nt][2] + acc4[nt][3]);
    v += __shfl_xor(v, 16, 64);
    v += __shfl_xor(v, 32, 64);
    acc[nt] = v;
  }

  // coalesced: lane (n,quad) stores column quad*16+n (one dword per lane)
  out[b * 64 + quad * 16 + n] = acc[quad] * (1.0f / (float)LL);
}

// ---------------------------------------------------------------------------
// Fallback (no workspace): all-fp32, one block per b, weights in padded LDS.
// ---------------------------------------------------------------------------
__global__ __launch_bounds__(256) void k_fallback(
    const float* __restrict__ v2e, const float* __restrict__ r2e,
    const float* __restrict__ w1W, const float* __restrict__ w1b,
    const float* __restrict__ w2W, const float* __restrict__ w2b,
    const int* __restrict__ huv, const int* __restrict__ hrr,
    float* __restrict__ out)
{
  __shared__ float sw1[64][129];
  __shared__ float sw2[64][65];
  __shared__ float sx[4][128];
  __shared__ float sh[4][64];
  __shared__ float red[4][64];

  const int tid = threadIdx.x;
  const int wave = tid >> 6, lane = tid & 63;
  const int b = blockIdx.x;

  for (int idx = tid; idx < 64 * 128; idx += 256) sw1[idx >> 7][idx & 127] = w1W[idx];
  for (int idx = tid; idx < 64 * 64; idx += 256) sw2[idx >> 6][idx & 63] = w2W[idx];
  __syncthreads();

  const float b1o = w1b[lane], b2o = w2b[lane];
  float acc = 0.f;

  for (int l = wave; l < LL; l += 4) {
    const int iv = huv[b * LL + l];
    const int ir = hrr[b * LL + l];
    sx[wave][lane]      = v2e[iv * 64 + lane];
    sx[wave][64 + lane] = r2e[ir * 64 + lane];
    __syncthreads();
    float h = b1o;
    for (int i = 0; i < 128; ++i) h += sx[wave][i] * sw1[lane][i];
    sh[wave][lane] = fmaxf(h, 0.f);
    __syncthreads();
    float o = b2o;
    for (int i = 0; i < 64; ++i) o += sh[wave][i] * sw2[lane][i];
    acc += fmaxf(o, 0.f);
  }

  red[wave][lane] = acc;
  __syncthreads();
  if (tid < 64) {
    const float s = red[0][tid] + red[1][tid] + red[2][tid] + red[3][tid];
    out[b * 64 + tid] = s * (1.0f / (float)LL);
  }
}

extern "C" void kernel_launch(void* const* d_in, const int* in_sizes, int n_in,
                              void* d_out, int out_size, void* d_ws, size_t ws_size,
                              hipStream_t stream) {
  (void)in_sizes; (void)n_in; (void)out_size;
  const float* v2e = (const float*)d_in[0];   // [100000,64]
  const float* r2e = (const float*)d_in[1];   // [5,64]
  const float* w1W = (const float*)d_in[2];   // [64,128]
  const float* w1b = (const float*)d_in[3];   // [64]
  const float* w2W = (const float*)d_in[4];   // [64,64]
  const float* w2b = (const float*)d_in[5];   // [64]
  // d_in[6] = nodes (unused by uv=True branch)
  const int* huv = (const int*)d_in[7];       // [4096,200]
  const int* hrr = (const int*)d_in[8];       // [4096,200]
  float* out = (float*)d_out;                 // [4096,64]

  const size_t OFF_R5 = (size_t)NITEMS * 64;                   // 6,400,000 (fp8 table)
  const size_t OFF_W2 = OFF_R5 + NRATE * 64 * sizeof(float);   // +1,280
  const size_t NEED   = OFF_W2 + 64 * 64 * sizeof(short);      // +8,192

  if (ws_size >= NEED) {
    unsigned char* pre8 = (unsigned char*)d_ws;
    float* r5p = (float*)((char*)d_ws + OFF_R5);
    short* w2p = (short*)((char*)d_ws + OFF_W2);

    k_pre<<<783, 256, 0, stream>>>(v2e, r2e, w1W, w1b, w2W, pre8, w2p, r5p);
    k_main<<<BB / 4, 256, 0, stream>>>(pre8, r5p, w2p, w2b, huv, hrr, out);
  } else {
    k_fallback<<<BB, 256, 0, stream>>>(v2e, r2e, w1W, w1b, w2W, w2b, huv, hrr, out);
  }
}